// Round 4
// baseline (2204.486 us; speedup 1.0000x reference)
//
#include <hip/hip_runtime.h>
#include <math.h>
#include <type_traits>

#define S_ 2048
#define E_ 1024
#define H_ 16
#define FF_ 4096
#define MB_ 2048   // rows per batch chunk

typedef unsigned short u16;
typedef unsigned int u32;
typedef __attribute__((ext_vector_type(8))) short short8;
typedef __attribute__((ext_vector_type(8))) __bf16 bf16x8;
typedef __attribute__((ext_vector_type(4))) float f32x4;

__device__ __forceinline__ float bf2f(u16 u){
  union { u32 i; float f; } v; v.i = ((u32)u) << 16; return v.f;
}
__device__ __forceinline__ u16 f2bf(float f){
  union { float f; u32 i; } v; v.f = f;
  u32 i = v.i + 0x7FFF + ((v.i >> 16) & 1);   // RNE
  return (u16)(i >> 16);
}
__device__ __forceinline__ f32x4 mfma_bf16(short8 a, short8 b, f32x4 c){
  return __builtin_amdgcn_mfma_f32_16x16x32_bf16(
      __builtin_bit_cast(bf16x8, a), __builtin_bit_cast(bf16x8, b), c, 0, 0, 0);
}

// ---------------- rope table: cos/sin[s][d], s<2048, d<32 ----------------
__global__ __launch_bounds__(256) void rope_tab_k(float* __restrict__ ct, float* __restrict__ st){
  int i = blockIdx.x * 256 + threadIdx.x;   // 65536 entries
  int s = i >> 5, d = i & 31;
  float ang = (float)s * __expf(-(float)d * 0.28782313662425575f); // 10000^(-d/32)
  float sn, cs; sincosf(ang, &sn, &cs);
  ct[i] = cs; st[i] = sn;
}

// ---------------- layernorm: fp32 in, bf16 out (rows of E=1024) ----------------
__global__ __launch_bounds__(256) void layernorm_k(const float* __restrict__ x,
                                                   const float* __restrict__ g,
                                                   const float* __restrict__ be,
                                                   u16* __restrict__ out){
  int row = blockIdx.x;
  int tid = threadIdx.x;
  const float* xr = x + (size_t)row * E_;
  float4 d = *(const float4*)&xr[tid * 4];
  float v0 = d.x, v1 = d.y, v2 = d.z, v3 = d.w;
  float s  = v0 + v1 + v2 + v3;
  float s2 = v0*v0 + v1*v1 + v2*v2 + v3*v3;
  #pragma unroll
  for (int off = 32; off; off >>= 1){
    s  += __shfl_xor(s, off, 64);
    s2 += __shfl_xor(s2, off, 64);
  }
  __shared__ float red[8];
  int w = tid >> 6;
  if ((tid & 63) == 0){ red[w] = s; red[4 + w] = s2; }
  __syncthreads();
  s  = red[0] + red[1] + red[2] + red[3];
  s2 = red[4] + red[5] + red[6] + red[7];
  float mu = s * (1.f / E_);
  float rstd = rsqrtf(fmaxf(s2 * (1.f / E_) - mu * mu, 0.f) + 1e-5f);
  float4 gg = *(const float4*)&g[tid * 4];
  float4 bb = *(const float4*)&be[tid * 4];
  float o0 = (v0 - mu) * rstd * gg.x + bb.x;
  float o1 = (v1 - mu) * rstd * gg.y + bb.y;
  float o2 = (v2 - mu) * rstd * gg.z + bb.z;
  float o3 = (v3 - mu) * rstd * gg.w + bb.w;
  uint2 r;
  r.x = (u32)f2bf(o0) | ((u32)f2bf(o1) << 16);
  r.y = (u32)f2bf(o2) | ((u32)f2bf(o3) << 16);
  *(uint2*)&out[(size_t)row * E_ + tid * 4] = r;
}

// ---------------- GEMM: C(M,N) = A(M,K)[bf16] @ B(K,N)[fp32] + epilogue ----------------
// B fp32 native (K,N); converted to bf16 during LDS staging with an XOR swizzle
// (store col k^(((n>>4)&3)<<3), read block lq^(j&3)) keeping ds_read_b128 hot.
// 128x128 tile, BK=32, 4 waves each 64x64 (4x4 of 16x16x32 MFMA).
// EPI: 0=bias->bf16, 1=bias+extra(fp32)->fp32, 2=gelu(bias+)->bf16, 3=(bias+)*extra(bf16)->bf16
#define LDST 40   // padded LDS row stride (elements); 80 B keeps 16-B alignment

template<int EPI>
__global__ __launch_bounds__(256) void gemm_nn(const u16* __restrict__ A,
                                               const float* __restrict__ B,
                                               const float* __restrict__ bias,
                                               const void* __restrict__ extra_,
                                               void* __restrict__ C_,
                                               int M, int N, int K){
  using ET = std::conditional_t<EPI == 1, float, u16>;
  using CT = std::conditional_t<EPI == 1, float, u16>;
  const ET* extra = (const ET*)extra_;
  CT* C = (CT*)C_;

  __shared__ u16 As[128 * LDST];
  __shared__ u16 Bs[128 * LDST];
  const int tid = threadIdx.x;
  const int n0 = blockIdx.x * 128;
  const int m0 = blockIdx.y * 128;
  const int wave = tid >> 6, lane = tid & 63;
  const int wr = (wave >> 1) * 64, wc = (wave & 1) * 64;
  const int lr = lane & 15, lq = lane >> 4;
  f32x4 acc[4][4];
  #pragma unroll
  for (int i = 0; i < 4; i++)
    #pragma unroll
    for (int j = 0; j < 4; j++) acc[i][j] = (f32x4){0.f, 0.f, 0.f, 0.f};

  const int asr = tid >> 2;         // 0..63
  const int asc = (tid & 3) * 8;    // 0,8,16,24
  const u16* Ap = A + (size_t)(m0 + asr) * K + asc;
  const int bkr = tid >> 3;         // 0..31 (k row within tile)
  const int bnc = (tid & 7) * 16;   // 0..112 (n col within tile)
  const float* Bp = B + (size_t)bkr * N + n0 + bnc;
  const int bcol = bkr ^ (((bnc >> 4) & 3) << 3);  // swizzled k-slot

  for (int k0 = 0; k0 < K; k0 += 32){
    uint4 a0 = *(const uint4*)(Ap + k0);
    uint4 a1 = *(const uint4*)(Ap + (size_t)64 * K + k0);
    float4 b0 = *(const float4*)(Bp + (size_t)k0 * N);
    float4 b1 = *(const float4*)(Bp + (size_t)k0 * N + 4);
    float4 b2 = *(const float4*)(Bp + (size_t)k0 * N + 8);
    float4 b3 = *(const float4*)(Bp + (size_t)k0 * N + 12);
    *(uint4*)&As[asr * LDST + asc]        = a0;
    *(uint4*)&As[(asr + 64) * LDST + asc] = a1;
    u16 bu[16];
    bu[0]=f2bf(b0.x); bu[1]=f2bf(b0.y); bu[2]=f2bf(b0.z); bu[3]=f2bf(b0.w);
    bu[4]=f2bf(b1.x); bu[5]=f2bf(b1.y); bu[6]=f2bf(b1.z); bu[7]=f2bf(b1.w);
    bu[8]=f2bf(b2.x); bu[9]=f2bf(b2.y); bu[10]=f2bf(b2.z); bu[11]=f2bf(b2.w);
    bu[12]=f2bf(b3.x); bu[13]=f2bf(b3.y); bu[14]=f2bf(b3.z); bu[15]=f2bf(b3.w);
    #pragma unroll
    for (int i = 0; i < 16; i++)
      Bs[(bnc + i) * LDST + bcol] = bu[i];
    __syncthreads();
    short8 af[4], bfr[4];
    #pragma unroll
    for (int i = 0; i < 4; i++)
      af[i] = *(const short8*)&As[(wr + i*16 + lr) * LDST + lq * 8];
    #pragma unroll
    for (int j = 0; j < 4; j++)
      bfr[j] = *(const short8*)&Bs[(wc + j*16 + lr) * LDST + (lq ^ (j & 3)) * 8];
    #pragma unroll
    for (int i = 0; i < 4; i++)
      #pragma unroll
      for (int j = 0; j < 4; j++)
        acc[i][j] = mfma_bf16(af[i], bfr[j], acc[i][j]);
    __syncthreads();
  }
  // epilogue: C/D layout col=lane&15, row=(lane>>4)*4+reg  [m89/m91 verified]
  #pragma unroll
  for (int i = 0; i < 4; i++){
    #pragma unroll
    for (int r = 0; r < 4; r++){
      int m = m0 + wr + i*16 + lq*4 + r;
      #pragma unroll
      for (int j = 0; j < 4; j++){
        int n = n0 + wc + j*16 + lr;
        float v = acc[i][j][r] + bias[n];
        if (EPI == 1){
          v += ((const float*)extra)[(size_t)m * N + n];
          ((float*)C)[(size_t)m * N + n] = v;
        } else if (EPI == 2){
          v = 0.5f * v * (1.f + erff(v * 0.70710678118654752f));
          ((u16*)C)[(size_t)m * N + n] = f2bf(v);
        } else if (EPI == 3){
          v = v * bf2f(((const u16*)extra)[(size_t)m * N + n]);
          ((u16*)C)[(size_t)m * N + n] = f2bf(v);
        } else {
          ((u16*)C)[(size_t)m * N + n] = f2bf(v);
        }
      }
    }
  }
}

// ---------------- sliding-window flash attention, fused RoPE, one batch ----------------
// reads qkv (MB_,3E) bf16 internal; grid (S/64, H), 256 thr (4 waves x 16 q-rows).
// window |i-j|<=128 -> 5 key chunks of 64. O written bf16 (MB_,E).
__global__ __launch_bounds__(256) void attn_k(const u16* __restrict__ QKV,
                                              const float* __restrict__ ctab,
                                              const float* __restrict__ stab,
                                              u16* __restrict__ O){
  const int qt = blockIdx.x, h = blockIdx.y;
  const int q0 = qt * 64;

  __shared__ float Qs[64][68];   // fp32, roped, pre-scaled by 1/8
  __shared__ float Ps[64][68];
  __shared__ u16  Ks[64][72];    // roped bf16; 144-B rows keep 16-B alignment
  __shared__ u16  Vs[64][72];

  const int tid = threadIdx.x;
  const int wave = tid >> 6, lane = tid & 63;
  const int r = tid >> 2, j4 = tid & 3;
  const int d0 = j4 * 8, c16 = j4 * 16;

  auto unpack8 = [](uint4 u, float* f){
    f[0]=bf2f(u.x&0xffff); f[1]=bf2f(u.x>>16);
    f[2]=bf2f(u.y&0xffff); f[3]=bf2f(u.y>>16);
    f[4]=bf2f(u.z&0xffff); f[5]=bf2f(u.z>>16);
    f[6]=bf2f(u.w&0xffff); f[7]=bf2f(u.w>>16);
  };

  { // Q: load + rope + scale -> fp32 LDS
    int s = q0 + r;
    const u16* qp = QKV + (size_t)s * 3072 + h * 64;
    float x1[8], x2[8], cc[8], sn[8];
    unpack8(*(const uint4*)(qp + d0), x1);
    unpack8(*(const uint4*)(qp + d0 + 32), x2);
    *(float4*)&cc[0] = *(const float4*)(ctab + s * 32 + d0);
    *(float4*)&cc[4] = *(const float4*)(ctab + s * 32 + d0 + 4);
    *(float4*)&sn[0] = *(const float4*)(stab + s * 32 + d0);
    *(float4*)&sn[4] = *(const float4*)(stab + s * 32 + d0 + 4);
    #pragma unroll
    for (int i = 0; i < 8; i++){
      Qs[r][d0 + i]      = (x1[i]*cc[i] - x2[i]*sn[i]) * 0.125f;
      Qs[r][d0 + 32 + i] = (x2[i]*cc[i] + x1[i]*sn[i]) * 0.125f;
    }
  }
  float m_i[16], l_i[16], o_acc[16];
  #pragma unroll
  for (int i = 0; i < 16; i++){ m_i[i] = -1e30f; l_i[i] = 0.f; o_acc[i] = 0.f; }
  __syncthreads();

  for (int ch = 0; ch < 5; ch++){
    int kb = q0 - 128 + ch * 64;
    { // stage K (roped, bf16) and V; clamped rows get masked later
      int sk = min(max(kb + r, 0), S_ - 1);
      const u16* kp = QKV + (size_t)sk * 3072 + 1024 + h * 64;
      const u16* vp = kp + 1024;
      float x1[8], x2[8], cc[8], sn[8];
      unpack8(*(const uint4*)(kp + d0), x1);
      unpack8(*(const uint4*)(kp + d0 + 32), x2);
      *(float4*)&cc[0] = *(const float4*)(ctab + sk * 32 + d0);
      *(float4*)&cc[4] = *(const float4*)(ctab + sk * 32 + d0 + 4);
      *(float4*)&sn[0] = *(const float4*)(stab + sk * 32 + d0);
      *(float4*)&sn[4] = *(const float4*)(stab + sk * 32 + d0 + 4);
      short8 lo, hi;
      #pragma unroll
      for (int i = 0; i < 8; i++){
        lo[i] = (short)f2bf(x1[i]*cc[i] - x2[i]*sn[i]);
        hi[i] = (short)f2bf(x2[i]*cc[i] + x1[i]*sn[i]);
      }
      *(short8*)&Ks[r][d0]      = lo;
      *(short8*)&Ks[r][d0 + 32] = hi;
      *(uint4*)&Vs[r][c16]     = *(const uint4*)(vp + c16);
      *(uint4*)&Vs[r][c16 + 8] = *(const uint4*)(vp + c16 + 8);
    }
    __syncthreads();

    // ---- scores: lane = key ----
    float kreg[64];
    #pragma unroll
    for (int t = 0; t < 8; t++){
      uint4 kr = *(const uint4*)&Ks[lane][t * 8];
      kreg[t*8+0]=bf2f(kr.x&0xffff); kreg[t*8+1]=bf2f(kr.x>>16);
      kreg[t*8+2]=bf2f(kr.y&0xffff); kreg[t*8+3]=bf2f(kr.y>>16);
      kreg[t*8+4]=bf2f(kr.z&0xffff); kreg[t*8+5]=bf2f(kr.z>>16);
      kreg[t*8+6]=bf2f(kr.w&0xffff); kreg[t*8+7]=bf2f(kr.w>>16);
    }
    int kg = kb + lane;
    bool kin = (kg >= 0) && (kg < S_);
    #pragma unroll
    for (int i = 0; i < 16; i++){
      int srow = q0 + wave * 16 + i;
      const float4* qr = (const float4*)&Qs[wave * 16 + i][0];
      float sc = 0.f;
      #pragma unroll
      for (int t = 0; t < 16; t++){
        float4 qv = qr[t];
        sc += qv.x*kreg[t*4+0] + qv.y*kreg[t*4+1] + qv.z*kreg[t*4+2] + qv.w*kreg[t*4+3];
      }
      int diff = kg - srow;
      bool valid = kin && diff >= -128 && diff <= 128;
      sc = valid ? sc : -1e30f;
      float mx = sc;
      #pragma unroll
      for (int off = 32; off; off >>= 1) mx = fmaxf(mx, __shfl_xor(mx, off, 64));
      float m_new = fmaxf(m_i[i], mx);
      float alpha = __expf(m_i[i] - m_new);
      float p = valid ? __expf(sc - m_new) : 0.f;
      float ps = p;
      #pragma unroll
      for (int off = 32; off; off >>= 1) ps += __shfl_xor(ps, off, 64);
      l_i[i] = l_i[i] * alpha + ps;
      m_i[i] = m_new;
      o_acc[i] *= alpha;
      Ps[wave * 16 + i][lane] = p;
    }
    __syncthreads();

    // ---- PV: lane = d ----
    float vreg[64];
    #pragma unroll
    for (int j = 0; j < 64; j++) vreg[j] = bf2f(Vs[j][lane]);
    #pragma unroll
    for (int i = 0; i < 16; i++){
      const float4* pr = (const float4*)&Ps[wave * 16 + i][0];
      float sum = 0.f;
      #pragma unroll
      for (int t = 0; t < 16; t++){
        float4 pv = pr[t];
        sum += pv.x*vreg[t*4+0] + pv.y*vreg[t*4+1] + pv.z*vreg[t*4+2] + pv.w*vreg[t*4+3];
      }
      o_acc[i] += sum;
    }
    __syncthreads();
  }
  #pragma unroll
  for (int i = 0; i < 16; i++){
    int srow = q0 + wave * 16 + i;
    O[(size_t)srow * E_ + h * 64 + lane] = f2bf(o_acc[i] / l_i[i]);
  }
}

// ---------------- launch ----------------
extern "C" void kernel_launch(void* const* d_in, const int* in_sizes, int n_in,
                              void* d_out, int out_size, void* d_ws, size_t ws_size,
                              hipStream_t stream){
  const float* src    = (const float*)d_in[0];
  const float* Wqkv   = (const float*)d_in[1];
  const float* bqkv   = (const float*)d_in[2];
  const float* Wout   = (const float*)d_in[3];
  const float* bout   = (const float*)d_in[4];
  const float* gamma1 = (const float*)d_in[5];
  const float* beta1  = (const float*)d_in[6];
  const float* gamma2 = (const float*)d_in[7];
  const float* beta2  = (const float*)d_in[8];
  const float* Wg     = (const float*)d_in[9];
  const float* bg     = (const float*)d_in[10];
  const float* Wv     = (const float*)d_in[11];
  const float* bv     = (const float*)d_in[12];
  const float* Wo     = (const float*)d_in[13];
  const float* bo     = (const float*)d_in[14];
  float* out = (float*)d_out;
  u16* ws  = (u16*)d_ws;

  // ws layout: 20.5 MiB
  u16* RA     = ws;                        // 2,097,152 el bf16: LN out / attn out
  u16* RC     = RA + 2097152;              // 8,388,608 el bf16: qkv (2048x3072) -> FFN act (2048x4096)
  float* ctab = (float*)(RC + 8388608);    // 65,536 fp32
  float* stab = ctab + 65536;              // 65,536 fp32

  dim3 t256(256);
  rope_tab_k<<<dim3(256), t256, 0, stream>>>(ctab, stab);

  for (int b = 0; b < 4; b++){
    const float* srcb = src + (size_t)b * MB_ * E_;
    float* outb = out + (size_t)b * MB_ * E_;
    // LN1 (fp32 in -> bf16 RA)
    layernorm_k<<<dim3(MB_), t256, 0, stream>>>(srcb, gamma1, beta1, RA);
    // QKV projection -> RC (bf16)
    gemm_nn<0><<<dim3(24, 16), t256, 0, stream>>>(RA, Wqkv, bqkv, nullptr, RC, MB_, 3072, 1024);
    // attention (RoPE fused) -> RA (bf16)
    attn_k<<<dim3(32, 16), t256, 0, stream>>>(RC, ctab, stab, RA);
    // out-proj + residual(src fp32) -> x1 in outb (fp32)
    gemm_nn<1><<<dim3(8, 16), t256, 0, stream>>>(RA, Wout, bout, srcb, outb, MB_, 1024, 1024);
    // LN2 (fp32 outb -> bf16 RA)
    layernorm_k<<<dim3(MB_), t256, 0, stream>>>(outb, gamma2, beta2, RA);
    // FFN: gate = gelu(h2@Wg+bg) -> RC (bf16); then RC = (h2@Wv+bv)*RC
    gemm_nn<2><<<dim3(32, 16), t256, 0, stream>>>(RA, Wg, bg, nullptr, RC, MB_, 4096, 1024);
    gemm_nn<3><<<dim3(32, 16), t256, 0, stream>>>(RA, Wv, bv, RC, RC, MB_, 4096, 1024);
    // down-proj + bias + residual(x1=outb fp32) -> outb (fp32)
    gemm_nn<1><<<dim3(8, 16), t256, 0, stream>>>(RC, Wo, bo, outb, outb, MB_, 1024, 4096);
  }

  (void)in_sizes; (void)n_in; (void)out_size; (void)ws_size;
}

// Round 5
// 686.096 us; speedup vs baseline: 3.2131x; 3.2131x over previous
//
#include <hip/hip_runtime.h>
#include <math.h>
#include <type_traits>

#define S_ 2048
#define E_ 1024
#define H_ 16
#define FF_ 4096
#define MB_ 2048   // rows per batch chunk
#define M_  8192   // all batches

typedef unsigned short u16;
typedef unsigned int u32;
typedef __attribute__((ext_vector_type(8))) short short8;
typedef __attribute__((ext_vector_type(8))) __bf16 bf16x8;
typedef __attribute__((ext_vector_type(4))) float f32x4;

__device__ __forceinline__ float bf2f(u16 u){
  union { u32 i; float f; } v; v.i = ((u32)u) << 16; return v.f;
}
__device__ __forceinline__ u16 f2bf(float f){
  union { float f; u32 i; } v; v.f = f;
  u32 i = v.i + 0x7FFF + ((v.i >> 16) & 1);   // RNE
  return (u16)(i >> 16);
}
__device__ __forceinline__ f32x4 mfma_bf16(short8 a, short8 b, f32x4 c){
  return __builtin_amdgcn_mfma_f32_16x16x32_bf16(
      __builtin_bit_cast(bf16x8, a), __builtin_bit_cast(bf16x8, b), c, 0, 0, 0);
}
__device__ __forceinline__ void unpack8(uint4 u, float* f){
  f[0]=bf2f(u.x&0xffff); f[1]=bf2f(u.x>>16);
  f[2]=bf2f(u.y&0xffff); f[3]=bf2f(u.y>>16);
  f[4]=bf2f(u.z&0xffff); f[5]=bf2f(u.z>>16);
  f[6]=bf2f(u.w&0xffff); f[7]=bf2f(u.w>>16);
}

// ---------------- rope table: cos/sin[s][d], s<2048, d<32 ----------------
__global__ __launch_bounds__(256) void rope_tab_k(float* __restrict__ ct, float* __restrict__ st){
  int i = blockIdx.x * 256 + threadIdx.x;   // 65536 entries
  int s = i >> 5, d = i & 31;
  float ang = (float)s * __expf(-(float)d * 0.28782313662425575f); // 10000^(-d/32)
  float sn, cs; sincosf(ang, &sn, &cs);
  ct[i] = cs; st[i] = sn;
}

// ---------------- weight transpose+convert: fp32 (R,C) -> bf16 (C,R) ----------------
__global__ __launch_bounds__(1024) void wtrans_k(const float* __restrict__ in,
                                                 u16* __restrict__ out, int R, int C){
  __shared__ u16 tile[64][65];
  int c0 = blockIdx.x * 64, r0 = blockIdx.y * 64;
  int tx = threadIdx.x & 63, ty = threadIdx.x >> 6;   // 64 x 16
  for (int i = ty; i < 64; i += 16)
    tile[i][tx] = f2bf(in[(size_t)(r0 + i) * C + c0 + tx]);
  __syncthreads();
  for (int i = ty; i < 64; i += 16)
    out[(size_t)(c0 + i) * R + r0 + tx] = tile[tx][i];
}

// ---------------- layernorm: fp32 in, bf16 out (rows of E=1024) ----------------
__global__ __launch_bounds__(256) void layernorm_k(const float* __restrict__ x,
                                                   const float* __restrict__ g,
                                                   const float* __restrict__ be,
                                                   u16* __restrict__ out){
  int row = blockIdx.x;
  int tid = threadIdx.x;
  const float* xr = x + (size_t)row * E_;
  float4 d = *(const float4*)&xr[tid * 4];
  float v0 = d.x, v1 = d.y, v2 = d.z, v3 = d.w;
  float s  = v0 + v1 + v2 + v3;
  float s2 = v0*v0 + v1*v1 + v2*v2 + v3*v3;
  #pragma unroll
  for (int off = 32; off; off >>= 1){
    s  += __shfl_xor(s, off, 64);
    s2 += __shfl_xor(s2, off, 64);
  }
  __shared__ float red[8];
  int w = tid >> 6;
  if ((tid & 63) == 0){ red[w] = s; red[4 + w] = s2; }
  __syncthreads();
  s  = red[0] + red[1] + red[2] + red[3];
  s2 = red[4] + red[5] + red[6] + red[7];
  float mu = s * (1.f / E_);
  float rstd = rsqrtf(fmaxf(s2 * (1.f / E_) - mu * mu, 0.f) + 1e-5f);
  float4 gg = *(const float4*)&g[tid * 4];
  float4 bb = *(const float4*)&be[tid * 4];
  float o0 = (v0 - mu) * rstd * gg.x + bb.x;
  float o1 = (v1 - mu) * rstd * gg.y + bb.y;
  float o2 = (v2 - mu) * rstd * gg.z + bb.z;
  float o3 = (v3 - mu) * rstd * gg.w + bb.w;
  uint2 r;
  r.x = (u32)f2bf(o0) | ((u32)f2bf(o1) << 16);
  r.y = (u32)f2bf(o2) | ((u32)f2bf(o3) << 16);
  *(uint2*)&out[(size_t)row * E_ + tid * 4] = r;
}

// ======== GEMM (path A): C = A(M,K)[bf16] @ BT(N,K)[bf16]^T + epilogue ========
// m93 structure: 128x128 tile, BK=32, 4 waves of 4x4 16x16x32 MFMA, uint4 staging.
// EPI: 0=bias->bf16, 1=bias+extra(fp32)->fp32, 2=gelu->bf16, 3=*extra(bf16)->bf16
#define LDST 40

template<int EPI>
__global__ __launch_bounds__(256) void gemm_bt(const u16* __restrict__ A,
                                               const u16* __restrict__ BT,
                                               const float* __restrict__ bias,
                                               const void* __restrict__ extra_,
                                               void* __restrict__ C_,
                                               int M, int N, int K){
  __shared__ u16 As[128 * LDST];
  __shared__ u16 Bs[128 * LDST];
  const int tid = threadIdx.x;
  const int n0 = blockIdx.x * 128;
  const int m0 = blockIdx.y * 128;
  const int wave = tid >> 6, lane = tid & 63;
  const int wr = (wave >> 1) * 64, wc = (wave & 1) * 64;
  const int lr = lane & 15, lq = lane >> 4;
  f32x4 acc[4][4];
  #pragma unroll
  for (int i = 0; i < 4; i++)
    #pragma unroll
    for (int j = 0; j < 4; j++) acc[i][j] = (f32x4){0.f, 0.f, 0.f, 0.f};

  const int sr = tid >> 2;
  const int sc = (tid & 3) * 8;
  const u16* Ap = A  + (size_t)(m0 + sr) * K + sc;
  const u16* Bp = BT + (size_t)(n0 + sr) * K + sc;

  for (int k0 = 0; k0 < K; k0 += 32){
    *(uint4*)&As[sr * LDST + sc]        = *(const uint4*)(Ap + k0);
    *(uint4*)&As[(sr + 64) * LDST + sc] = *(const uint4*)(Ap + (size_t)64 * K + k0);
    *(uint4*)&Bs[sr * LDST + sc]        = *(const uint4*)(Bp + k0);
    *(uint4*)&Bs[(sr + 64) * LDST + sc] = *(const uint4*)(Bp + (size_t)64 * K + k0);
    __syncthreads();
    short8 af[4], bfr[4];
    #pragma unroll
    for (int i = 0; i < 4; i++) af[i]  = *(const short8*)&As[(wr + i*16 + lr) * LDST + lq*8];
    #pragma unroll
    for (int j = 0; j < 4; j++) bfr[j] = *(const short8*)&Bs[(wc + j*16 + lr) * LDST + lq*8];
    #pragma unroll
    for (int i = 0; i < 4; i++)
      #pragma unroll
      for (int j = 0; j < 4; j++)
        acc[i][j] = mfma_bf16(af[i], bfr[j], acc[i][j]);
    __syncthreads();
  }
  #pragma unroll
  for (int i = 0; i < 4; i++){
    #pragma unroll
    for (int r = 0; r < 4; r++){
      int m = m0 + wr + i*16 + lq*4 + r;
      #pragma unroll
      for (int j = 0; j < 4; j++){
        int n = n0 + wc + j*16 + lr;
        float v = acc[i][j][r] + bias[n];
        if (EPI == 1){
          v += ((const float*)extra_)[(size_t)m * N + n];
          ((float*)C_)[(size_t)m * N + n] = v;
        } else if (EPI == 2){
          v = 0.5f * v * (1.f + erff(v * 0.70710678118654752f));
          ((u16*)C_)[(size_t)m * N + n] = f2bf(v);
        } else if (EPI == 3){
          v = v * bf2f(((const u16*)extra_)[(size_t)m * N + n]);
          ((u16*)C_)[(size_t)m * N + n] = f2bf(v);
        } else {
          ((u16*)C_)[(size_t)m * N + n] = f2bf(v);
        }
      }
    }
  }
}

// ======== GEMM (path B fallback): B fp32 native (K,N), round-4 verified ========
template<int EPI>
__global__ __launch_bounds__(256) void gemm_nn(const u16* __restrict__ A,
                                               const float* __restrict__ B,
                                               const float* __restrict__ bias,
                                               const void* __restrict__ extra_,
                                               void* __restrict__ C_,
                                               int M, int N, int K){
  __shared__ u16 As[128 * LDST];
  __shared__ u16 Bs[128 * LDST];
  const int tid = threadIdx.x;
  const int n0 = blockIdx.x * 128;
  const int m0 = blockIdx.y * 128;
  const int wave = tid >> 6, lane = tid & 63;
  const int wr = (wave >> 1) * 64, wc = (wave & 1) * 64;
  const int lr = lane & 15, lq = lane >> 4;
  f32x4 acc[4][4];
  #pragma unroll
  for (int i = 0; i < 4; i++)
    #pragma unroll
    for (int j = 0; j < 4; j++) acc[i][j] = (f32x4){0.f, 0.f, 0.f, 0.f};

  const int asr = tid >> 2;
  const int asc = (tid & 3) * 8;
  const u16* Ap = A + (size_t)(m0 + asr) * K + asc;
  const int bkr = tid >> 3;
  const int bnc = (tid & 7) * 16;
  const float* Bp = B + (size_t)bkr * N + n0 + bnc;
  const int bcol = bkr ^ (((bnc >> 4) & 3) << 3);

  for (int k0 = 0; k0 < K; k0 += 32){
    uint4 a0 = *(const uint4*)(Ap + k0);
    uint4 a1 = *(const uint4*)(Ap + (size_t)64 * K + k0);
    float4 b0 = *(const float4*)(Bp + (size_t)k0 * N);
    float4 b1 = *(const float4*)(Bp + (size_t)k0 * N + 4);
    float4 b2 = *(const float4*)(Bp + (size_t)k0 * N + 8);
    float4 b3 = *(const float4*)(Bp + (size_t)k0 * N + 12);
    *(uint4*)&As[asr * LDST + asc]        = a0;
    *(uint4*)&As[(asr + 64) * LDST + asc] = a1;
    u16 bu[16];
    bu[0]=f2bf(b0.x); bu[1]=f2bf(b0.y); bu[2]=f2bf(b0.z); bu[3]=f2bf(b0.w);
    bu[4]=f2bf(b1.x); bu[5]=f2bf(b1.y); bu[6]=f2bf(b1.z); bu[7]=f2bf(b1.w);
    bu[8]=f2bf(b2.x); bu[9]=f2bf(b2.y); bu[10]=f2bf(b2.z); bu[11]=f2bf(b2.w);
    bu[12]=f2bf(b3.x); bu[13]=f2bf(b3.y); bu[14]=f2bf(b3.z); bu[15]=f2bf(b3.w);
    #pragma unroll
    for (int i = 0; i < 16; i++)
      Bs[(bnc + i) * LDST + bcol] = bu[i];
    __syncthreads();
    short8 af[4], bfr[4];
    #pragma unroll
    for (int i = 0; i < 4; i++)
      af[i] = *(const short8*)&As[(wr + i*16 + lr) * LDST + lq * 8];
    #pragma unroll
    for (int j = 0; j < 4; j++)
      bfr[j] = *(const short8*)&Bs[(wc + j*16 + lr) * LDST + (lq ^ (j & 3)) * 8];
    #pragma unroll
    for (int i = 0; i < 4; i++)
      #pragma unroll
      for (int j = 0; j < 4; j++)
        acc[i][j] = mfma_bf16(af[i], bfr[j], acc[i][j]);
    __syncthreads();
  }
  #pragma unroll
  for (int i = 0; i < 4; i++){
    #pragma unroll
    for (int r = 0; r < 4; r++){
      int m = m0 + wr + i*16 + lq*4 + r;
      #pragma unroll
      for (int j = 0; j < 4; j++){
        int n = n0 + wc + j*16 + lr;
        float v = acc[i][j][r] + bias[n];
        if (EPI == 1){
          v += ((const float*)extra_)[(size_t)m * N + n];
          ((float*)C_)[(size_t)m * N + n] = v;
        } else if (EPI == 2){
          v = 0.5f * v * (1.f + erff(v * 0.70710678118654752f));
          ((u16*)C_)[(size_t)m * N + n] = f2bf(v);
        } else if (EPI == 3){
          v = v * bf2f(((const u16*)extra_)[(size_t)m * N + n]);
          ((u16*)C_)[(size_t)m * N + n] = f2bf(v);
        } else {
          ((u16*)C_)[(size_t)m * N + n] = f2bf(v);
        }
      }
    }
  }
}

// ============ MFMA sliding-window flash attention, fused RoPE ============
// grid (32, H, nbatch), 256 thr = 4 waves; wave w owns q columns w*16..w*16+15.
// S^T = K·Q^T per 64-key chunk (A=K rows, B=Q rows, both b128 from LDS);
// softmax per q-column: 16 keys in-lane + shfl_xor(16,32) across quads;
// P -> LDS [q][key] -> B-frags; V transposed at staging -> A-frags.
__global__ __launch_bounds__(256) void attn_k(const u16* __restrict__ QKV,
                                              const float* __restrict__ ctab,
                                              const float* __restrict__ stab,
                                              u16* __restrict__ O){
  const int qt = blockIdx.x, h = blockIdx.y, bz = blockIdx.z;
  const int q0 = qt * 64;
  const size_t rowbase = (size_t)bz * MB_;

  __shared__ u16 Qs[64][72];   // roped bf16, pre-scaled by 1/8  [q][d]
  __shared__ u16 Ks[64][72];   // roped bf16                      [key][d]
  __shared__ u16 VT[64][72];   // transposed                      [d][key]
  __shared__ u16 Ps[64][72];   // probabilities bf16              [q][key]

  const int tid = threadIdx.x;
  const int w = tid >> 6, lane = tid & 63;
  const int lr = lane & 15, quad = lane >> 4;
  const int r = tid >> 2, j4 = tid & 3;
  const int d0 = j4 * 8, c16 = j4 * 16;

  { // Q: load + rope + scale -> bf16 LDS
    int s = q0 + r;
    const u16* qp = QKV + (rowbase + s) * 3072 + h * 64;
    float x1[8], x2[8], cc[8], sn[8];
    unpack8(*(const uint4*)(qp + d0), x1);
    unpack8(*(const uint4*)(qp + d0 + 32), x2);
    *(float4*)&cc[0] = *(const float4*)(ctab + s * 32 + d0);
    *(float4*)&cc[4] = *(const float4*)(ctab + s * 32 + d0 + 4);
    *(float4*)&sn[0] = *(const float4*)(stab + s * 32 + d0);
    *(float4*)&sn[4] = *(const float4*)(stab + s * 32 + d0 + 4);
    #pragma unroll
    for (int i = 0; i < 8; i++){
      Qs[r][d0 + i]      = f2bf((x1[i]*cc[i] - x2[i]*sn[i]) * 0.125f);
      Qs[r][d0 + 32 + i] = f2bf((x2[i]*cc[i] + x1[i]*sn[i]) * 0.125f);
    }
  }
  __syncthreads();

  // Q B-frags for this wave (n = q = w*16+lr, k = d = quad*8 (+32))
  short8 bq0 = *(const short8*)&Qs[w*16 + lr][quad*8];
  short8 bq1 = *(const short8*)&Qs[w*16 + lr][quad*8 + 32];
  const int qg = q0 + w*16 + lr;   // this lane's q column (global s index)

  float m_i = -1e30f, l_i = 0.f;
  f32x4 ot[4];
  #pragma unroll
  for (int t = 0; t < 4; t++) ot[t] = (f32x4){0.f, 0.f, 0.f, 0.f};

  for (int ch = 0; ch < 5; ch++){
    int kb = q0 - 128 + ch * 64;
    { // stage K (roped bf16 rows) and V (transposed) ; clamped rows masked later
      int sk = min(max(kb + r, 0), S_ - 1);
      const u16* kp = QKV + (rowbase + sk) * 3072 + 1024 + h * 64;
      const u16* vp = kp + 1024;
      float x1[8], x2[8], cc[8], sn[8];
      unpack8(*(const uint4*)(kp + d0), x1);
      unpack8(*(const uint4*)(kp + d0 + 32), x2);
      *(float4*)&cc[0] = *(const float4*)(ctab + sk * 32 + d0);
      *(float4*)&cc[4] = *(const float4*)(ctab + sk * 32 + d0 + 4);
      *(float4*)&sn[0] = *(const float4*)(stab + sk * 32 + d0);
      *(float4*)&sn[4] = *(const float4*)(stab + sk * 32 + d0 + 4);
      #pragma unroll
      for (int i = 0; i < 8; i++){
        Ks[r][d0 + i]      = f2bf(x1[i]*cc[i] - x2[i]*sn[i]);
        Ks[r][d0 + 32 + i] = f2bf(x2[i]*cc[i] + x1[i]*sn[i]);
      }
      uint4 v0 = *(const uint4*)(vp + c16);
      uint4 v1 = *(const uint4*)(vp + c16 + 8);
      union { uint4 q[2]; u16 u[16]; } vv; vv.q[0] = v0; vv.q[1] = v1;
      #pragma unroll
      for (int i = 0; i < 16; i++)
        VT[c16 + i][r] = vv.u[i];
    }
    __syncthreads();

    // ---- scores S^T[key][q]: 4 key-tiles x (2 MFMA) ----
    f32x4 st[4];
    #pragma unroll
    for (int t = 0; t < 4; t++){
      short8 ak0 = *(const short8*)&Ks[t*16 + lr][quad*8];
      short8 ak1 = *(const short8*)&Ks[t*16 + lr][quad*8 + 32];
      f32x4 z = (f32x4){0.f, 0.f, 0.f, 0.f};
      z = mfma_bf16(ak0, bq0, z);
      st[t] = mfma_bf16(ak1, bq1, z);
    }
    // ---- mask + column max ----
    float mx = -1e30f;
    bool ok[4][4];
    #pragma unroll
    for (int t = 0; t < 4; t++){
      #pragma unroll
      for (int rg = 0; rg < 4; rg++){
        int kg = kb + t*16 + quad*4 + rg;
        int diff = kg - qg;
        ok[t][rg] = (kg >= 0) && (kg < S_) && (diff >= -128) && (diff <= 128);
        float v = ok[t][rg] ? st[t][rg] : -1e30f;
        st[t][rg] = v;
        mx = fmaxf(mx, v);
      }
    }
    mx = fmaxf(mx, __shfl_xor(mx, 16, 64));
    mx = fmaxf(mx, __shfl_xor(mx, 32, 64));
    float m_new = fmaxf(m_i, mx);
    float alpha = __expf(m_i - m_new);
    // ---- p + write P to Ps[q][key] + column sum ----
    float psum = 0.f;
    #pragma unroll
    for (int t = 0; t < 4; t++){
      float p0 = ok[t][0] ? __expf(st[t][0] - m_new) : 0.f;
      float p1 = ok[t][1] ? __expf(st[t][1] - m_new) : 0.f;
      float p2 = ok[t][2] ? __expf(st[t][2] - m_new) : 0.f;
      float p3 = ok[t][3] ? __expf(st[t][3] - m_new) : 0.f;
      psum += (p0 + p1) + (p2 + p3);
      uint2 pk;
      pk.x = (u32)f2bf(p0) | ((u32)f2bf(p1) << 16);
      pk.y = (u32)f2bf(p2) | ((u32)f2bf(p3) << 16);
      *(uint2*)&Ps[w*16 + lr][t*16 + quad*4] = pk;
    }
    psum += __shfl_xor(psum, 16, 64);
    psum += __shfl_xor(psum, 32, 64);
    l_i = l_i * alpha + psum;
    m_i = m_new;
    // ---- PV: O^T[d][q] += V^T[d][key] · P^T[key][q] (in-wave LDS RAW, auto lgkmcnt) ----
    short8 bp0 = *(const short8*)&Ps[w*16 + lr][quad*8];
    short8 bp1 = *(const short8*)&Ps[w*16 + lr][quad*8 + 32];
    #pragma unroll
    for (int td = 0; td < 4; td++){
      short8 av0 = *(const short8*)&VT[td*16 + lr][quad*8];
      short8 av1 = *(const short8*)&VT[td*16 + lr][quad*8 + 32];
      f32x4 o = ot[td] * alpha;
      o = mfma_bf16(av0, bp0, o);
      ot[td] = mfma_bf16(av1, bp1, o);
    }
    __syncthreads();
  }
  // ---- write O: lane holds q=qg, d = td*16+quad*4+{0..3} ----
  float inv_l = 1.f / l_i;
  u16* orow = O + (rowbase + qg) * E_ + h * 64;
  #pragma unroll
  for (int td = 0; td < 4; td++){
    uint2 pk;
    pk.x = (u32)f2bf(ot[td][0] * inv_l) | ((u32)f2bf(ot[td][1] * inv_l) << 16);
    pk.y = (u32)f2bf(ot[td][2] * inv_l) | ((u32)f2bf(ot[td][3] * inv_l) << 16);
    *(uint2*)&orow[td*16 + quad*4] = pk;
  }
}

// ---------------- launch ----------------
extern "C" void kernel_launch(void* const* d_in, const int* in_sizes, int n_in,
                              void* d_out, int out_size, void* d_ws, size_t ws_size,
                              hipStream_t stream){
  const float* src    = (const float*)d_in[0];
  const float* Wqkv   = (const float*)d_in[1];
  const float* bqkv   = (const float*)d_in[2];
  const float* Wout   = (const float*)d_in[3];
  const float* bout   = (const float*)d_in[4];
  const float* gamma1 = (const float*)d_in[5];
  const float* beta1  = (const float*)d_in[6];
  const float* gamma2 = (const float*)d_in[7];
  const float* beta2  = (const float*)d_in[8];
  const float* Wg     = (const float*)d_in[9];
  const float* bg     = (const float*)d_in[10];
  const float* Wv     = (const float*)d_in[11];
  const float* bv     = (const float*)d_in[12];
  const float* Wo     = (const float*)d_in[13];
  const float* bo     = (const float*)d_in[14];
  float* out = (float*)d_out;
  u16* ws  = (u16*)d_ws;

  dim3 t256(256), t1024(1024);

  // Path A needs: Wt 33,554,432 + RA 16,777,216 + RC 67,108,864 + tabs 524,288
  const size_t NEED_A = 33554432ull + 16777216ull + 67108864ull + 524288ull;

  if (ws_size >= NEED_A){
    // ---------- batched path ----------
    u16* WqkvT = ws;                          // (3072,1024) bf16
    u16* WoutT = WqkvT + 3145728;             // (1024,1024)
    u16* WgT   = WoutT + 1048576;             // (4096,1024)
    u16* WvT   = WgT   + 4194304;             // (4096,1024)
    u16* WoT   = WvT   + 4194304;             // (1024,4096)
    u16* RA    = WoT   + 4194304;             // 8,388,608 el bf16 (M,E)
    u16* RC    = RA    + 8388608;             // 33,554,432 el bf16 (M,FF max)
    float* ctab = (float*)(RC + 33554432);
    float* stab = ctab + 65536;

    rope_tab_k<<<dim3(256), t256, 0, stream>>>(ctab, stab);
    wtrans_k<<<dim3(48, 16), t1024, 0, stream>>>(Wqkv, WqkvT, 1024, 3072);
    wtrans_k<<<dim3(16, 16), t1024, 0, stream>>>(Wout, WoutT, 1024, 1024);
    wtrans_k<<<dim3(64, 16), t1024, 0, stream>>>(Wg,   WgT,   1024, 4096);
    wtrans_k<<<dim3(64, 16), t1024, 0, stream>>>(Wv,   WvT,   1024, 4096);
    wtrans_k<<<dim3(16, 64), t1024, 0, stream>>>(Wo,   WoT,   4096, 1024);

    layernorm_k<<<dim3(M_), t256, 0, stream>>>(src, gamma1, beta1, RA);
    gemm_bt<0><<<dim3(24, 64), t256, 0, stream>>>(RA, WqkvT, bqkv, nullptr, RC, M_, 3072, 1024);
    attn_k<<<dim3(32, 16, 4), t256, 0, stream>>>(RC, ctab, stab, RA);
    gemm_bt<1><<<dim3(8, 64), t256, 0, stream>>>(RA, WoutT, bout, src, out, M_, 1024, 1024);
    layernorm_k<<<dim3(M_), t256, 0, stream>>>(out, gamma2, beta2, RA);
    gemm_bt<2><<<dim3(32, 64), t256, 0, stream>>>(RA, WgT, bg, nullptr, RC, M_, 4096, 1024);
    gemm_bt<3><<<dim3(32, 64), t256, 0, stream>>>(RA, WvT, bv, RC, RC, M_, 4096, 1024);
    gemm_bt<1><<<dim3(8, 64), t256, 0, stream>>>(RC, WoT, bo, out, out, M_, 1024, 4096);
  } else {
    // ---------- per-batch fallback (round-4 structure, 20.5 MiB) ----------
    u16* RA     = ws;                        // 2,097,152 el bf16
    u16* RC     = RA + 2097152;              // 8,388,608 el bf16
    float* ctab = (float*)(RC + 8388608);
    float* stab = ctab + 65536;

    rope_tab_k<<<dim3(256), t256, 0, stream>>>(ctab, stab);
    for (int b = 0; b < 4; b++){
      const float* srcb = src + (size_t)b * MB_ * E_;
      float* outb = out + (size_t)b * MB_ * E_;
      layernorm_k<<<dim3(MB_), t256, 0, stream>>>(srcb, gamma1, beta1, RA);
      gemm_nn<0><<<dim3(24, 16), t256, 0, stream>>>(RA, Wqkv, bqkv, nullptr, RC, MB_, 3072, 1024);
      attn_k<<<dim3(32, 16, 1), t256, 0, stream>>>(RC, ctab, stab, RA);
      gemm_nn<1><<<dim3(8, 16), t256, 0, stream>>>(RA, Wout, bout, srcb, outb, MB_, 1024, 1024);
      layernorm_k<<<dim3(MB_), t256, 0, stream>>>(outb, gamma2, beta2, RA);
      gemm_nn<2><<<dim3(32, 16), t256, 0, stream>>>(RA, Wg, bg, nullptr, RC, MB_, 4096, 1024);
      gemm_nn<3><<<dim3(32, 16), t256, 0, stream>>>(RA, Wv, bv, RC, RC, MB_, 4096, 1024);
      gemm_nn<1><<<dim3(8, 16), t256, 0, stream>>>(RC, Wo, bo, outb, outb, MB_, 1024, 4096);
    }
  }

  (void)in_sizes; (void)n_in; (void)out_size;
}